// Round 3
// baseline (146.642 us; speedup 1.0000x reference)
//
#include <hip/hip_runtime.h>

#define NJ   16
#define DM   128
#define NH   8
#define HDIM 16
#define P    4          // positions per block
#define NPASS 2         // 2 positions processed concurrently per pass

// Kinematic adjacency (compile-time constant of the reference).
__constant__ __align__(16) float c_adj[NJ * NJ] = {
    1,1,0,0, 1,0,0,1, 0,0,1,0, 0,1,0,0,
    1,1,1,0, 0,0,0,0, 0,0,0,0, 0,0,0,0,
    0,1,1,1, 0,0,0,0, 0,0,0,0, 0,0,0,0,
    0,0,1,1, 0,0,0,0, 0,0,0,0, 0,0,0,0,
    1,0,0,0, 1,1,0,0.8f, 0,0,0,0, 0,0,0,0,
    0,0,0,0, 1,1,1,0, 0.8f,0,0,0, 0,0,0,0,
    0,0,0,0, 0,1,1,0, 0,0.8f,0,0, 0,0,0,0,
    1,0,0,0, 0.8f,0,0,1, 1,0,0,0, 0,0,0,0,
    0,0,0,0, 0,0.8f,0,1, 1,1,0,0, 0,0,0,0,
    0,0,0,0, 0,0,0.8f,0, 1,1,0,0, 0,0,0,0,
    1,0,0,0, 0,0,0,0, 0,0,1,1, 0,0.8f,0,0,
    0,0,0,0, 0,0,0,0, 0,0,1,1, 1,0,0.8f,0,
    0,0,0,0, 0,0,0,0, 0,0,0,1, 1,0,0,0.8f,
    1,0,0,0, 0,0,0,0, 0,0,0.8f,0, 0,1,1,0,
    0,0,0,0, 0,0,0,0, 0,0,0,0.8f, 0,1,1,1,
    0,0,0,0, 0,0,0,0, 0,0,0,0, 0.8f,0,1,1
};

// ws layout (floats):
//   [0, 3072)      G[24][128]   : G[h*3+r][n] = sum_dh Wv[r][h*16+dh] * Wo[h*16+dh][n]
//   [3072, 3200)   bprime[128]  : bv @ Wo + bo
//   [3200, 3328)   pack[8][16]  : per head: M(9, row-major), a(3), c(3), d(1)
#define WS_BP   3072
#define WS_PACK 3200

__global__ __launch_bounds__(256) void skel_setup_kernel(
    const float* __restrict__ Wq, const float* __restrict__ bq,
    const float* __restrict__ Wk, const float* __restrict__ bk,
    const float* __restrict__ Wv, const float* __restrict__ bv,
    const float* __restrict__ Wo, const float* __restrict__ bo,
    float* __restrict__ ws)
{
    const int b = blockIdx.x, t = threadIdx.x;
    if (b < 12) {
        // two G-rows per block
        const int hr = b * 2 + (t >> 7);
        const int n  = t & 127;
        const int h = hr / 3, r = hr % 3;
        float acc = 0.f;
#pragma unroll
        for (int dh = 0; dh < HDIM; ++dh)
            acc += Wv[r * DM + h * HDIM + dh] * Wo[(h * HDIM + dh) * DM + n];
        ws[hr * DM + n] = acc;
        return;
    }
    // block 12: b' and per-head packs
    if (t < 128) {
        const int n = t;
        float bv_ = bo[n];
        for (int d = 0; d < DM; ++d) bv_ += bv[d] * Wo[d * DM + n];
        ws[WS_BP + n] = bv_;
    } else if (t < 128 + NH) {
        const int h = t - 128;
        float* o = &ws[WS_PACK + h * 16];
#pragma unroll
        for (int r = 0; r < 3; ++r)
#pragma unroll
            for (int c = 0; c < 3; ++c) {
                float acc = 0.f;
#pragma unroll
                for (int dh = 0; dh < HDIM; ++dh)
                    acc += Wq[r * DM + h * HDIM + dh] * Wk[c * DM + h * HDIM + dh];
                o[r * 3 + c] = acc;
            }
#pragma unroll
        for (int r = 0; r < 3; ++r) {
            float aa = 0.f, cc = 0.f;
#pragma unroll
            for (int dh = 0; dh < HDIM; ++dh) {
                aa += Wq[r * DM + h * HDIM + dh] * bk[h * HDIM + dh];
                cc += Wk[r * DM + h * HDIM + dh] * bq[h * HDIM + dh];
            }
            o[9 + r]  = aa;
            o[12 + r] = cc;
        }
        float dd = 0.f;
#pragma unroll
        for (int dh = 0; dh < HDIM; ++dh) dd += bq[h * HDIM + dh] * bk[h * HDIM + dh];
        o[15] = dd;
    }
}

__device__ __forceinline__ float dot4(float4 a, float4 b) {
    return a.x * b.x + a.y * b.y + a.z * b.z + a.w * b.w;
}

__global__ __launch_bounds__(256, 5) void skel_main_kernel(
    const float* __restrict__ x,
    const float* __restrict__ ws,
    float* __restrict__ out,
    int npos)
{
    const int t = threadIdx.x;
    const long pos0 = (long)blockIdx.x * P;

    __shared__ float sx[P][48];                       // x per position
    __shared__ float sc[128];                         // per-head packs
    __shared__ __align__(16) float st[2][NH][17][4];  // {M x_k (3), c·x_k + d}; k padded 16->17
    __shared__ __align__(16) float sXB[2 * NJ][24];   // xbar for the 2 in-flight positions

    // ---- stage x and constants ----------------------------------------
    if (t < P * 48) {
        const long gi = pos0 * 48 + t;
        sx[t / 48][t % 48] = (gi < (long)npos * 48) ? x[gi] : 0.f;
    }
    if (t < 128) sc[t] = ws[WS_PACK + t];
    __syncthreads();

    const int p2  = t >> 7;          // 0..1 (wave-uniform)
    const int rem = t & 127;
    const int h   = rem >> 4;
    const int kj  = rem & 15;        // k in t-phase, j in score phase
    const float* Mh = &sc[h * 16];
    const int n = rem;               // out-phase column

    for (int pass = 0; pass < NPASS; ++pass) {
        const int p = pass * 2 + p2;
        const float x0 = sx[p][kj * 3 + 0];
        const float x1 = sx[p][kj * 3 + 1];
        const float x2 = sx[p][kj * 3 + 2];

        // ---- t-phase: t_k = M_h x_k ; e_k = c_h·x_k + d_h --------------
        st[p2][h][kj][0] = Mh[0] * x0 + Mh[1] * x1 + Mh[2] * x2;
        st[p2][h][kj][1] = Mh[3] * x0 + Mh[4] * x1 + Mh[5] * x2;
        st[p2][h][kj][2] = Mh[6] * x0 + Mh[7] * x1 + Mh[8] * x2;
        st[p2][h][kj][3] = Mh[12] * x0 + Mh[13] * x1 + Mh[14] * x2 + Mh[15];
        __syncthreads();   // B1

        // ---- score + softmax + xbar (j = kj) ---------------------------
        {
            const int j = kj;
            const float u = Mh[9] * x0 + Mh[10] * x1 + Mh[11] * x2;  // a_h·x_j

            const float4* adjq = (const float4*)&c_adj[j * NJ];
            const float4 a0 = adjq[0], a1 = adjq[1], a2 = adjq[2], a3 = adjq[3];
            float adjr[NJ] = { a0.x,a0.y,a0.z,a0.w, a1.x,a1.y,a1.z,a1.w,
                               a2.x,a2.y,a2.z,a2.w, a3.x,a3.y,a3.z,a3.w };

            float s[NJ];
            float mx = -1e30f;
#pragma unroll
            for (int k = 0; k < NJ; ++k) {
                const float4 tk = *(const float4*)&st[p2][h][k][0];
                float sv = x0 * tk.x + x1 * tk.y + x2 * tk.z + tk.w + u;
                sv = (sv + adjr[k]) * 0.25f;
                s[k] = sv;
                mx = fmaxf(mx, sv);
            }
            float sum = 0.f;
#pragma unroll
            for (int k = 0; k < NJ; ++k) {
                const float e = __expf(s[k] - mx);
                s[k] = e;
                sum += e;
            }
            const float inv = 1.f / sum;

            float xb0 = 0.f, xb1 = 0.f, xb2 = 0.f;
#pragma unroll
            for (int k = 0; k < NJ; ++k) {
                const float wk = s[k] * inv;
                xb0 += wk * sx[p][k * 3 + 0];
                xb1 += wk * sx[p][k * 3 + 1];
                xb2 += wk * sx[p][k * 3 + 2];
            }
            float* xbp = &sXB[p2 * NJ + j][h * 3];
            xbp[0] = xb0; xbp[1] = xb1; xbp[2] = xb2;
        }
        __syncthreads();   // B2: sXB published

        // ---- out for this pass's 2 positions (thread = (p2, col n)) ----
        {
            float g[24];
#pragma unroll
            for (int hr = 0; hr < 24; ++hr) g[hr] = ws[hr * DM + n];
            const float bp = ws[WS_BP + n];

            const long pidx = pos0 + pass * 2 + p2;
            if (pidx < npos) {
                float* op = out + pidx * (long)(NJ * DM) + n;
#pragma unroll
                for (int j2 = 0; j2 < NJ; ++j2) {
                    const float4* xq = (const float4*)&sXB[p2 * NJ + j2][0];
                    const float4 b0 = xq[0], b1 = xq[1], b2 = xq[2];
                    const float4 b3 = xq[3], b4 = xq[4], b5 = xq[5];
                    float acc = bp;
                    acc += b0.x*g[0]  + b0.y*g[1]  + b0.z*g[2]  + b0.w*g[3];
                    acc += b1.x*g[4]  + b1.y*g[5]  + b1.z*g[6]  + b1.w*g[7];
                    acc += b2.x*g[8]  + b2.y*g[9]  + b2.z*g[10] + b2.w*g[11];
                    acc += b3.x*g[12] + b3.y*g[13] + b3.z*g[14] + b3.w*g[15];
                    acc += b4.x*g[16] + b4.y*g[17] + b4.z*g[18] + b4.w*g[19];
                    acc += b5.x*g[20] + b5.y*g[21] + b5.z*g[22] + b5.w*g[23];
                    op[j2 * DM] = acc;
                }
            }
        }
        __syncthreads();   // B3: st + sXB reusable next pass
    }
}

extern "C" void kernel_launch(void* const* d_in, const int* in_sizes, int n_in,
                              void* d_out, int out_size, void* d_ws, size_t ws_size,
                              hipStream_t stream) {
    const float* x  = (const float*)d_in[0];
    const float* Wq = (const float*)d_in[1];
    const float* bq = (const float*)d_in[2];
    const float* Wk = (const float*)d_in[3];
    const float* bk = (const float*)d_in[4];
    const float* Wv = (const float*)d_in[5];
    const float* bv = (const float*)d_in[6];
    const float* Wo = (const float*)d_in[7];
    const float* bo = (const float*)d_in[8];
    float* out = (float*)d_out;
    float* ws  = (float*)d_ws;

    const int npos = in_sizes[0] / (NJ * 3);   // B*S
    skel_setup_kernel<<<13, 256, 0, stream>>>(Wq, bq, Wk, bk, Wv, bv, Wo, bo, ws);
    const int grid = (npos + P - 1) / P;
    skel_main_kernel<<<grid, 256, 0, stream>>>(x, ws, out, npos);
}

// Round 5
// 74.725 us; speedup vs baseline: 1.9624x; 1.9624x over previous
//
#include <hip/hip_runtime.h>

#define NJ   16
#define DM   128
#define NH   8
#define P    8          // positions per block
#define NPASS 4         // 2 positions per pass

typedef __attribute__((ext_vector_type(8))) short bf16x8;
typedef __attribute__((ext_vector_type(4))) float f32x4;

// Kinematic adjacency (compile-time constant of the reference).
__constant__ __align__(16) float c_adj[NJ * NJ] = {
    1,1,0,0, 1,0,0,1, 0,0,1,0, 0,1,0,0,
    1,1,1,0, 0,0,0,0, 0,0,0,0, 0,0,0,0,
    0,1,1,1, 0,0,0,0, 0,0,0,0, 0,0,0,0,
    0,0,1,1, 0,0,0,0, 0,0,0,0, 0,0,0,0,
    1,0,0,0, 1,1,0,0.8f, 0,0,0,0, 0,0,0,0,
    0,0,0,0, 1,1,1,0, 0.8f,0,0,0, 0,0,0,0,
    0,0,0,0, 0,1,1,0, 0,0.8f,0,0, 0,0,0,0,
    1,0,0,0, 0.8f,0,0,1, 1,0,0,0, 0,0,0,0,
    0,0,0,0, 0,0.8f,0,1, 1,1,0,0, 0,0,0,0,
    0,0,0,0, 0,0,0.8f,0, 1,1,0,0, 0,0,0,0,
    1,0,0,0, 0,0,0,0, 0,0,1,1, 0,0.8f,0,0,
    0,0,0,0, 0,0,0,0, 0,0,1,1, 1,0,0.8f,0,
    0,0,0,0, 0,0,0,0, 0,0,0,1, 1,0,0,0.8f,
    1,0,0,0, 0,0,0,0, 0,0,0.8f,0, 0,1,1,0,
    0,0,0,0, 0,0,0,0, 0,0,0,0.8f, 0,1,1,1,
    0,0,0,0, 0,0,0,0, 0,0,0,0, 0.8f,0,1,1
};

// ws layout (32-bit words):
//   [0,128)     bp[128] fp32        : bv @ Wo + bo
//   [128,256)   pack[8][16] fp32    : per head: M(9), a(3), c(3), d(1)
//   [256,2304)  Gfrag[8][64][4] u32 : bf16x2-packed B-fragments, k = 4h+r (r==3 -> 0)
#define WS_BP_W   0
#define WS_PACK_W 128
#define WS_GF_W   256

__device__ __forceinline__ unsigned short f2bf(float f) {
    union { float f; unsigned u; } v; v.f = f;
    unsigned u = v.u;
    u += 0x7FFFu + ((u >> 16) & 1u);          // RNE
    return (unsigned short)(u >> 16);
}
__device__ __forceinline__ unsigned pack2bf(float lo, float hi) {
    return (unsigned)f2bf(lo) | ((unsigned)f2bf(hi) << 16);
}

__global__ __launch_bounds__(256) void skel_setup_kernel(
    const float* __restrict__ Wq, const float* __restrict__ bq,
    const float* __restrict__ Wk, const float* __restrict__ bk,
    const float* __restrict__ Wv, const float* __restrict__ bv,
    const float* __restrict__ Wo, const float* __restrict__ bo,
    unsigned* __restrict__ wsu)
{
    const int b = blockIdx.x, t = threadIdx.x;
    float* wsf = (float*)wsu;

    if (b < 8) {
        // One packed u32 (2 bf16, k-pair) of Gfrag per thread.
        const int idx = b * 256 + t;          // 0..2047
        const int ctl = idx >> 2, i = idx & 3;
        const int ct = ctl >> 6, l = ctl & 63;
        const int n  = ct * 16 + (l & 15);
        const int kb = (l >> 4) * 8;
        float v[2];
#pragma unroll
        for (int s = 0; s < 2; ++s) {
            const int k = kb + 2 * i + s;
            const int h = k >> 2, r = k & 3;
            float acc = 0.f;
            if (r < 3) {
#pragma unroll
                for (int dh = 0; dh < 16; ++dh)
                    acc += Wv[r * DM + h * 16 + dh] * Wo[(h * 16 + dh) * DM + n];
            }
            v[s] = acc;
        }
        wsu[WS_GF_W + idx] = pack2bf(v[0], v[1]);
        return;
    }
    // block 8: bp and per-head packs
    if (t < 128) {
        const int n = t;
        float bv_ = bo[n];
        for (int d = 0; d < DM; ++d) bv_ += bv[d] * Wo[d * DM + n];
        wsf[WS_BP_W + n] = bv_;
    } else if (t < 128 + NH) {
        const int h = t - 128;
        float* o = &wsf[WS_PACK_W + h * 16];
#pragma unroll
        for (int r = 0; r < 3; ++r)
#pragma unroll
            for (int c = 0; c < 3; ++c) {
                float acc = 0.f;
#pragma unroll
                for (int dh = 0; dh < 16; ++dh)
                    acc += Wq[r * DM + h * 16 + dh] * Wk[c * DM + h * 16 + dh];
                o[r * 3 + c] = acc;
            }
#pragma unroll
        for (int r = 0; r < 3; ++r) {
            float aa = 0.f, cc = 0.f;
#pragma unroll
            for (int dh = 0; dh < 16; ++dh) {
                aa += Wq[r * DM + h * 16 + dh] * bk[h * 16 + dh];
                cc += Wk[r * DM + h * 16 + dh] * bq[h * 16 + dh];
            }
            o[9 + r]  = aa;
            o[12 + r] = cc;
        }
        float dd = 0.f;
#pragma unroll
        for (int dh = 0; dh < 16; ++dh) dd += bq[h * 16 + dh] * bk[h * 16 + dh];
        o[15] = dd;
    }
}

__global__ __launch_bounds__(256) void skel_main_kernel(
    const float* __restrict__ x,
    const unsigned* __restrict__ wsu,
    float* __restrict__ out,
    int npos)
{
    const int t = threadIdx.x;
    const long pos0 = (long)blockIdx.x * P;
    const float* wsf = (const float*)wsu;

    __shared__ float sx[P][48];                        // x per position
    __shared__ float sc[128];                          // per-head packs
    __shared__ __align__(16) float st[2][NH][17][4];   // {M x_k (3), c·x_k + d}
    __shared__ __align__(16) unsigned sxb[P * NJ][16]; // XB rows, bf16x2 words, K=32 padded
    __shared__ __align__(16) unsigned sgf[2048];       // G B-fragments (8 KB)
    __shared__ float sbp[128];                         // b'

    // ---- stage x and constants (loop: P*48 = 384 > 256 threads!) -------
    for (int i = t; i < P * 48; i += 256) {
        const long gi = pos0 * 48 + i;
        sx[i / 48][i % 48] = (gi < (long)npos * 48) ? x[gi] : 0.f;
    }
    if (t < 128) {
        sbp[t] = wsf[WS_BP_W + t];
        sc[t]  = wsf[WS_PACK_W + t];
    }
    {
        const uint4* gsrc = (const uint4*)&wsu[WS_GF_W];
        uint4* gdst = (uint4*)sgf;
        gdst[t]       = gsrc[t];
        gdst[t + 256] = gsrc[t + 256];
    }
    __syncthreads();

    const int p2  = t >> 7;          // 0..1 (wave-uniform)
    const int rem = t & 127;
    const int h   = rem >> 4;
    const int kj  = rem & 15;        // k in t-phase, j in score phase
    const float* Mh = &sc[h * 16];

    for (int pass = 0; pass < NPASS; ++pass) {
        const int p = pass * 2 + p2;
        const float x0 = sx[p][kj * 3 + 0];
        const float x1 = sx[p][kj * 3 + 1];
        const float x2 = sx[p][kj * 3 + 2];

        // ---- t-phase: t_k = M_h x_k ; e_k = c_h·x_k + d_h --------------
        st[p2][h][kj][0] = Mh[0] * x0 + Mh[1] * x1 + Mh[2] * x2;
        st[p2][h][kj][1] = Mh[3] * x0 + Mh[4] * x1 + Mh[5] * x2;
        st[p2][h][kj][2] = Mh[6] * x0 + Mh[7] * x1 + Mh[8] * x2;
        st[p2][h][kj][3] = Mh[12] * x0 + Mh[13] * x1 + Mh[14] * x2 + Mh[15];
        __syncthreads();   // B1

        // ---- score + softmax + xbar (j = kj) ---------------------------
        {
            const int j = kj;
            const float u = Mh[9] * x0 + Mh[10] * x1 + Mh[11] * x2;  // a_h·x_j

            const float4* adjq = (const float4*)&c_adj[j * NJ];
            const float4 a0 = adjq[0], a1 = adjq[1], a2 = adjq[2], a3 = adjq[3];
            float adjr[NJ] = { a0.x,a0.y,a0.z,a0.w, a1.x,a1.y,a1.z,a1.w,
                               a2.x,a2.y,a2.z,a2.w, a3.x,a3.y,a3.z,a3.w };

            float s[NJ];
            float mx = -1e30f;
#pragma unroll
            for (int k = 0; k < NJ; ++k) {
                const float4 tk = *(const float4*)&st[p2][h][k][0];
                float sv = x0 * tk.x + x1 * tk.y + x2 * tk.z + tk.w + u;
                sv = (sv + adjr[k]) * 0.25f;
                s[k] = sv;
                mx = fmaxf(mx, sv);
            }
            float sum = 0.f;
#pragma unroll
            for (int k = 0; k < NJ; ++k) {
                const float e = __expf(s[k] - mx);
                s[k] = e;
                sum += e;
            }
            const float inv = 1.f / sum;

            float xb0 = 0.f, xb1 = 0.f, xb2 = 0.f;
#pragma unroll
            for (int k = 0; k < NJ; ++k) {
                const float wk = s[k] * inv;
                xb0 += wk * sx[p][k * 3 + 0];
                xb1 += wk * sx[p][k * 3 + 1];
                xb2 += wk * sx[p][k * 3 + 2];
            }
            // bf16-pack into A-fragment-ready row (K = 32: k = 4h+r, r==3 pad 0)
            const int row = p * NJ + j;
            sxb[row][2 * h + 0] = pack2bf(xb0, xb1);
            sxb[row][2 * h + 1] = pack2bf(xb2, 0.f);
        }
        __syncthreads();   // B2
    }

    // ---- out phase: per wave, 2 row-tiles x 8 col-tiles of MFMA --------
    {
        const int wv = t >> 6, l = t & 63;
        const int lrow = l & 15, lk = l >> 4;

        float bpv[8];
#pragma unroll
        for (int ct = 0; ct < 8; ++ct) bpv[ct] = sbp[ct * 16 + lrow];

#pragma unroll
        for (int ri = 0; ri < 2; ++ri) {
            const int rt = wv * 2 + ri;                   // row-tile == position p
            if (pos0 + rt >= npos) continue;
            const bf16x8 a = *(const bf16x8*)&sxb[rt * 16 + lrow][lk * 4];
            float* obase = out + (pos0 + rt) * (long)(NJ * DM);
#pragma unroll
            for (int ct = 0; ct < 8; ++ct) {
                const bf16x8 bfr = *(const bf16x8*)&sgf[(ct * 64 + l) * 4];
                f32x4 acc = { bpv[ct], bpv[ct], bpv[ct], bpv[ct] };
                acc = __builtin_amdgcn_mfma_f32_16x16x32_bf16(a, bfr, acc, 0, 0, 0);
                const int col = ct * 16 + lrow;
#pragma unroll
                for (int r = 0; r < 4; ++r) {
                    const int jrow = lk * 4 + r;          // D row = (lane>>4)*4 + reg
                    obase[jrow * DM + col] = acc[r];
                }
            }
        }
    }
}

extern "C" void kernel_launch(void* const* d_in, const int* in_sizes, int n_in,
                              void* d_out, int out_size, void* d_ws, size_t ws_size,
                              hipStream_t stream) {
    const float* x  = (const float*)d_in[0];
    const float* Wq = (const float*)d_in[1];
    const float* bq = (const float*)d_in[2];
    const float* Wk = (const float*)d_in[3];
    const float* bk = (const float*)d_in[4];
    const float* Wv = (const float*)d_in[5];
    const float* bv = (const float*)d_in[6];
    const float* Wo = (const float*)d_in[7];
    const float* bo = (const float*)d_in[8];
    float* out    = (float*)d_out;
    unsigned* wsu = (unsigned*)d_ws;

    const int npos = in_sizes[0] / (NJ * 3);   // B*S
    skel_setup_kernel<<<9, 256, 0, stream>>>(Wq, bq, Wk, bk, Wv, bv, Wo, bo, wsu);
    const int grid = (npos + P - 1) / P;
    skel_main_kernel<<<grid, 256, 0, stream>>>(x, wsu, out, npos);
}